// Round 6
// baseline (213.999 us; speedup 1.0000x reference)
//
#include <hip/hip_runtime.h>

// Problem sizes (fixed by the reference)
constexpr int kB    = 2048;  // batch
constexpr int kVIS  = 2048;  // visible units (GEMM K)
constexpr int kHID  = 1024;  // hidden units (GEMM N)
constexpr int kCLS  = 64;    // classes
constexpr float kLog2e = 1.4426950408889634f;

typedef __attribute__((ext_vector_type(8))) short bf16x8;
typedef __attribute__((ext_vector_type(4))) float f32x4;
typedef __attribute__((ext_vector_type(2))) float f32x2;

typedef __attribute__((address_space(3))) unsigned       as3_u32;
typedef __attribute__((address_space(1))) const unsigned as1_u32;

__device__ __forceinline__ void g2lds16(const void* g, void* l) {
    // async global->LDS DMA, 16 B per lane; LDS dest is wave-base + lane*16
    __builtin_amdgcn_global_load_lds((as1_u32*)g, (as3_u32*)l, 16, 0, 0);
}

__device__ __forceinline__ unsigned short f2bf(float x) {
    unsigned u = __float_as_uint(x);
    u += 0x7fffu + ((u >> 16) & 1u);
    return (unsigned short)(u >> 16);
}
__device__ __forceinline__ float bf2f(unsigned short h) {
    return __uint_as_float(((unsigned)h) << 16);
}

// ---------------- Prep (merged): split v, split+transpose W, pack+scale U, zero ctrs ----
// blocks [0,4096): split_v ; [4096,6144): split_w_t ; [6144,6400): pack_u ; 6400: counters
__global__ __launch_bounds__(256) void prep_all(const float* __restrict__ v,
                                                const float* __restrict__ W,
                                                const float* __restrict__ U,
                                                unsigned short* __restrict__ vh,
                                                unsigned short* __restrict__ vl,
                                                unsigned short* __restrict__ wth,
                                                unsigned short* __restrict__ wtl,
                                                float* __restrict__ Utp,
                                                int* __restrict__ ctrs) {
    __shared__ float T[32][33];
    const int bx = blockIdx.x;
    if (bx < 4096) {
        const int i = (bx * 256 + threadIdx.x) * 4;
        const float4 xv = *(const float4*)(v + i);
        ushort4 h, l;
        h.x = f2bf(xv.x); l.x = f2bf(xv.x - bf2f(h.x));
        h.y = f2bf(xv.y); l.y = f2bf(xv.y - bf2f(h.y));
        h.z = f2bf(xv.z); l.z = f2bf(xv.z - bf2f(h.z));
        h.w = f2bf(xv.w); l.w = f2bf(xv.w - bf2f(h.w));
        *(ushort4*)(vh + i) = h;
        *(ushort4*)(vl + i) = l;
    } else if (bx < 6144) {
        const int b = bx - 4096;
        const int n0 = (b & 31) * 32, k0 = (b >> 5) * 32;
        const int c = threadIdx.x & 31, r0 = threadIdx.x >> 5;
#pragma unroll
        for (int p = 0; p < 4; ++p) {
            const int r = r0 + p * 8;
            T[r][c] = W[(size_t)(k0 + r) * kHID + n0 + c];
        }
        __syncthreads();
#pragma unroll
        for (int p = 0; p < 4; ++p) {
            const int rr = r0 + p * 8;          // n offset
            const float x = T[c][rr];           // = W[k0+c][n0+rr]
            const unsigned short h = f2bf(x);
            const unsigned short l = f2bf(x - bf2f(h));
            const size_t o = (size_t)(n0 + rr) * kVIS + k0 + c;
            wth[o] = h;
            wtl[o] = l;
        }
    } else if (bx < 6400) {
        const int id = (bx - 6144) * 256 + threadIdx.x;  // 0..65535
        const int j = id >> 6, y = id & 63;
        // packed: Utp[((j>>2)*64 + y)*4 + (j&3)]  ->  one dwordx4 per (j-quad, class)
        Utp[(((j >> 2) * kCLS + y) << 2) + (j & 3)] = U[(size_t)y * kHID + j] * kLog2e;
    } else {
        if (ctrs && threadIdx.x < 64) ctrs[threadIdx.x] = 0;
    }
}

// ---------------- Fused kernel: MFMA GEMM + softplus partials + last-block softmax ------
// 64x64 tile, 4 waves (32x32 quadrants, 2x2 of mfma_f32_16x16x32_bf16, 3 products).
// A (vh/vl) double-buffered in LDS (2 x 16KB, XOR-swizzled octets), ONE barrier per
// K=64 slab: DMA slab k+1 into idle buffer, compute slab k meanwhile.
// B (wth/wtl) loaded register-direct from global (L2-hot, k-contiguous dwordx4) —
// halves LDS-pipe traffic vs staging both operands (AITER/flatmm-style).
// Epilogue: ps[64][68] LDS overlay, packed-f32 softplus, Utp packed dwordx4.
// Last block per m-stripe (device atomic) reduces Fpart + softmax + argmax in-kernel.
__global__ __launch_bounds__(256) void gemm_fused(const unsigned short* __restrict__ vh,
                                                  const unsigned short* __restrict__ vl,
                                                  const unsigned short* __restrict__ wth,
                                                  const unsigned short* __restrict__ wtl,
                                                  const float* __restrict__ cvec,
                                                  const float* __restrict__ Utp,
                                                  const float* __restrict__ dvec,
                                                  float* __restrict__ Fpart,
                                                  int* __restrict__ ctrs,
                                                  float* __restrict__ out) {
    __shared__ __align__(16) union SMem {
        unsigned short stage[2][2][64 * 64];  // [buf][h/l][row][k]  (32768 B)
        float ps[64][68];                     // 17408 B, overlays stage
    } smem;
    __shared__ int lastFlag;

    const int tid = threadIdx.x;
    const int lane = tid & 63, wave = tid >> 6;
    const int m0 = blockIdx.y * 64, n0 = blockIdx.x * 64;
    const int wm = (wave >> 1) * 32, wn = (wave & 1) * 32;

    // A staging: thread covers rows r0 and r0+32; k-octet XOR-swizzled on global side
    const int r0 = tid >> 3, r1 = r0 + 32;
    const int oc = (((tid & 7) ^ ((tid >> 3) & 7)) << 3);   // global k-octet offset (elems)
    const size_t ga0 = (size_t)(m0 + r0) * kVIS + oc;
    const size_t ga1 = (size_t)(m0 + r1) * kVIS + oc;
    const int l0 = (r0 << 6) + ((tid & 7) << 3);            // physical LDS slot (elems)
    const int l1 = (r1 << 6) + ((tid & 7) << 3);

    // fragment addressing: A[m=lane&15][k], row-major LDK=64, swizzled octet
    const int fm = lane & 15, fq = lane >> 4;
    const int rx = fm & 7;
    const int a0r = (wm + fm) << 6,  a1r = (wm + 16 + fm) << 6;

    // B register-direct row bases (n-major layout)
    const size_t bg0 = (size_t)(n0 + wn + fm) * kVIS;
    const size_t bg1 = (size_t)(n0 + wn + 16 + fm) * kVIS;

    f32x4 acc[2][2] = {};

    // prime: DMA slab 0 into buffer 0
    g2lds16(vh + ga0, smem.stage[0][0] + l0);
    g2lds16(vh + ga1, smem.stage[0][0] + l1);
    g2lds16(vl + ga0, smem.stage[0][1] + l0);
    g2lds16(vl + ga1, smem.stage[0][1] + l1);
    __syncthreads();

    int cur = 0;
    for (int k0 = 0; k0 < kVIS; k0 += 64) {
        // prefetch next slab into the idle buffer (no barrier needed: disjoint buffer)
        if (k0 + 64 < kVIS) {
            unsigned short* Dh = smem.stage[cur ^ 1][0];
            unsigned short* Dl = smem.stage[cur ^ 1][1];
            g2lds16(vh + ga0 + k0 + 64, Dh + l0);
            g2lds16(vh + ga1 + k0 + 64, Dh + l1);
            g2lds16(vl + ga0 + k0 + 64, Dl + l0);
            g2lds16(vl + ga1 + k0 + 64, Dl + l1);
        }
        const unsigned short* Ah = smem.stage[cur][0];
        const unsigned short* Al = smem.stage[cur][1];
#pragma unroll
        for (int kk = 0; kk < 64; kk += 32) {
            const int kc = k0 + kk + fq * 8;
            // B fragments straight from global (L2-hot)
            const bf16x8 bh0 = *(const bf16x8*)(wth + bg0 + kc);
            const bf16x8 bh1 = *(const bf16x8*)(wth + bg1 + kc);
            const bf16x8 bl0 = *(const bf16x8*)(wtl + bg0 + kc);
            const bf16x8 bl1 = *(const bf16x8*)(wtl + bg1 + kc);
            // A fragments from LDS (swizzled octet)
            const int p = (((kk >> 3) + fq) ^ rx) << 3;
            const bf16x8 ah0 = *(const bf16x8*)(Ah + a0r + p);
            const bf16x8 ah1 = *(const bf16x8*)(Ah + a1r + p);
            const bf16x8 al0 = *(const bf16x8*)(Al + a0r + p);
            const bf16x8 al1 = *(const bf16x8*)(Al + a1r + p);
            acc[0][0] = __builtin_amdgcn_mfma_f32_16x16x32_bf16(ah0, bh0, acc[0][0], 0, 0, 0);
            acc[0][0] = __builtin_amdgcn_mfma_f32_16x16x32_bf16(ah0, bl0, acc[0][0], 0, 0, 0);
            acc[0][0] = __builtin_amdgcn_mfma_f32_16x16x32_bf16(al0, bh0, acc[0][0], 0, 0, 0);
            acc[0][1] = __builtin_amdgcn_mfma_f32_16x16x32_bf16(ah0, bh1, acc[0][1], 0, 0, 0);
            acc[0][1] = __builtin_amdgcn_mfma_f32_16x16x32_bf16(ah0, bl1, acc[0][1], 0, 0, 0);
            acc[0][1] = __builtin_amdgcn_mfma_f32_16x16x32_bf16(al0, bh1, acc[0][1], 0, 0, 0);
            acc[1][0] = __builtin_amdgcn_mfma_f32_16x16x32_bf16(ah1, bh0, acc[1][0], 0, 0, 0);
            acc[1][0] = __builtin_amdgcn_mfma_f32_16x16x32_bf16(ah1, bl0, acc[1][0], 0, 0, 0);
            acc[1][0] = __builtin_amdgcn_mfma_f32_16x16x32_bf16(al1, bh0, acc[1][0], 0, 0, 0);
            acc[1][1] = __builtin_amdgcn_mfma_f32_16x16x32_bf16(ah1, bh1, acc[1][1], 0, 0, 0);
            acc[1][1] = __builtin_amdgcn_mfma_f32_16x16x32_bf16(ah1, bl1, acc[1][1], 0, 0, 0);
            acc[1][1] = __builtin_amdgcn_mfma_f32_16x16x32_bf16(al1, bh1, acc[1][1], 0, 0, 0);
        }
        // one barrier per slab: next-slab DMA drained; all waves done with cur buffer
        __syncthreads();
        cur ^= 1;
    }

    // ---- epilogue phase 1: pre-tile -> ps (log2 domain, +c); 2-way writes (stride 68)
    // (loop's final barrier already guarantees all stage reads are done)
#pragma unroll
    for (int j = 0; j < 2; ++j) {
        const int col = wn + j * 16 + fm;              // local hid col 0..63
        const float cv = cvec[n0 + col];
#pragma unroll
        for (int i = 0; i < 2; ++i) {
            const int rbase = wm + i * 16 + fq * 4;    // local row
#pragma unroll
            for (int r = 0; r < 4; ++r)
                smem.ps[rbase + r][col] = (acc[i][j][r] + cv) * kLog2e;
        }
    }
    __syncthreads();

    // ---- epilogue phase 2: packed-f32 softplus; wave owns rows [wave*16,+16), lane=class
    const int q0 = (n0 >> 2);
    f32x2 relu2[16], prod2[16];
#pragma unroll
    for (int rr = 0; rr < 16; ++rr) { relu2[rr] = (f32x2)(0.f); prod2[rr] = (f32x2)(1.f); }

    const f32x2 zero2 = (f32x2)(0.f);
    for (int jc = 0; jc < 64; jc += 8) {
        const float4 ua = ((const float4*)Utp)[(q0 + (jc >> 2) + 0) * kCLS + lane];
        const float4 ub = ((const float4*)Utp)[(q0 + (jc >> 2) + 1) * kCLS + lane];
        const f32x2 u01 = {ua.x, ua.y}, u23 = {ua.z, ua.w};
        const f32x2 u45 = {ub.x, ub.y}, u67 = {ub.z, ub.w};
#pragma unroll
        for (int rr = 0; rr < 16; ++rr) {
            const float4 p0 = *(const float4*)&smem.ps[wave * 16 + rr][jc];      // broadcast
            const float4 p1 = *(const float4*)&smem.ps[wave * 16 + rr][jc + 4];  // broadcast
            f32x2 tp[4];
            tp[0] = (f32x2){p0.x, p0.y} + u01;
            tp[1] = (f32x2){p0.z, p0.w} + u23;
            tp[2] = (f32x2){p1.x, p1.y} + u45;
            tp[3] = (f32x2){p1.z, p1.w} + u67;
#pragma unroll
            for (int g = 0; g < 4; ++g) {
                const f32x2 t = tp[g];
                f32x2 e;
                e.x = __builtin_amdgcn_exp2f(-__builtin_fabsf(t.x));
                e.y = __builtin_amdgcn_exp2f(-__builtin_fabsf(t.y));
                prod2[rr] = __builtin_elementwise_fma(prod2[rr], e, prod2[rr]);  // *= (1+e), <=2^32/half
                relu2[rr] += __builtin_elementwise_max(t, zero2);
            }
        }
    }
#pragma unroll
    for (int rr = 0; rr < 16; ++rr) {
        const float contrib = relu2[rr].x + relu2[rr].y +
                              __builtin_amdgcn_logf(prod2[rr].x * prod2[rr].y);  // log2 domain
        Fpart[((size_t)blockIdx.x * kB + m0 + wave * 16 + rr) * kCLS + lane] = contrib;
    }

    // ---- last-block-done: the 16th block of this m-stripe finishes softmax/argmax ----
    if (!ctrs) return;
    __syncthreads();  // all Fpart stores issued by all waves
    if (tid == 0) {
        __threadfence();                                    // release our Fpart writes
        lastFlag = (atomicAdd(&ctrs[blockIdx.y], 1) == 15); // device-scope
    }
    __syncthreads();
    if (!lastFlag) return;
    __threadfence();  // acquire other blocks' Fpart writes

    for (int rr = 0; rr < 16; ++rr) {
        const int row = m0 + wave * 16 + rr;
        double s = 0.0;
#pragma unroll
        for (int kc = 0; kc < 16; ++kc)
            s += (double)Fpart[((size_t)kc * kB + row) * kCLS + lane];
        const float G = (float)s + dvec[lane] * kLog2e;  // log2-domain logit
        float m = G;
        int mi = lane;
#pragma unroll
        for (int off = 32; off; off >>= 1) {
            const float om = __shfl_xor(m, off);
            const int   oi = __shfl_xor(mi, off);
            if (om > m || (om == m && oi < mi)) { m = om; mi = oi; }  // first-idx tie-break
        }
        const float e2 = __builtin_amdgcn_exp2f(G - m);
        float ssum = e2;
#pragma unroll
        for (int off = 32; off; off >>= 1) ssum += __shfl_xor(ssum, off);
        out[(size_t)row * kCLS + lane] = e2 / ssum;
        out[(size_t)kB * kCLS + (size_t)row * kCLS + lane] = (lane == mi) ? 1.0f : 0.0f;
    }
}

// ---------------- Final: standalone softmax (used only if ws too small for counters) ----
__global__ __launch_bounds__(256) void softmax_final(const float* __restrict__ Fpart,
                                                     const float* __restrict__ dvec,
                                                     float* __restrict__ out) {
    const int tid = threadIdx.x;
    const int lane = tid & 63, wave = tid >> 6;
    const int row = blockIdx.x * 4 + wave;
    double s = 0.0;
#pragma unroll
    for (int k = 0; k < kHID / 64; ++k)
        s += (double)Fpart[((size_t)k * kB + row) * kCLS + lane];
    const float G = (float)s + dvec[lane] * kLog2e;
    float m = G;
    int mi = lane;
#pragma unroll
    for (int off = 32; off; off >>= 1) {
        const float om = __shfl_xor(m, off);
        const int   oi = __shfl_xor(mi, off);
        if (om > m || (om == m && oi < mi)) { m = om; mi = oi; }
    }
    const float e2 = __builtin_amdgcn_exp2f(G - m);
    float ssum = e2;
#pragma unroll
    for (int off = 32; off; off >>= 1) ssum += __shfl_xor(ssum, off);
    out[(size_t)row * kCLS + lane] = e2 / ssum;
    out[(size_t)kB * kCLS + (size_t)row * kCLS + lane] = (lane == mi) ? 1.0f : 0.0f;
}

// ================= Fallback (round-1, known-passing) if ws is too small =================
constexpr int BM = 64, BN = 64, BK = 16;

__global__ __launch_bounds__(256) void gemm_vw(const float* __restrict__ V,
                                               const float* __restrict__ Wm,
                                               const float* __restrict__ cvec,
                                               float* __restrict__ pre) {
    __shared__ float As[BK][BM + 4];
    __shared__ float Bs[BK][BN + 4];
    const int tid = threadIdx.x;
    const int tx = tid & 15, ty = tid >> 4;
    const int m0 = blockIdx.y * BM, n0 = blockIdx.x * BN;
    const int arow = tid >> 2, acol = (tid & 3) << 2;
    const int brow = tid >> 4, bcol = (tid & 15) << 2;
    const float* vptr = V + (size_t)(m0 + arow) * kVIS + acol;
    const float* wptr = Wm + (size_t)brow * kHID + n0 + bcol;
    float acc[4][4] = {};
    for (int k0 = 0; k0 < kVIS; k0 += BK) {
        const float4 a4 = *(const float4*)(vptr + k0);
        const float4 b4 = *(const float4*)(wptr + (size_t)k0 * kHID);
        __syncthreads();
        As[acol + 0][arow] = a4.x; As[acol + 1][arow] = a4.y;
        As[acol + 2][arow] = a4.z; As[acol + 3][arow] = a4.w;
        *(float4*)&Bs[brow][bcol] = b4;
        __syncthreads();
#pragma unroll
        for (int k = 0; k < BK; ++k) {
            const float4 av = *(const float4*)&As[k][ty << 2];
            const float4 bv = *(const float4*)&Bs[k][tx << 2];
            const float a[4] = {av.x, av.y, av.z, av.w};
            const float b[4] = {bv.x, bv.y, bv.z, bv.w};
#pragma unroll
            for (int i = 0; i < 4; ++i)
#pragma unroll
                for (int j = 0; j < 4; ++j) acc[i][j] += a[i] * b[j];
        }
    }
#pragma unroll
    for (int i = 0; i < 4; ++i) {
        const int row = m0 + (ty << 2) + i;
        const int col = n0 + (tx << 2);
        const float4 cv = *(const float4*)(cvec + col);
        float4 o;
        o.x = acc[i][0] + cv.x; o.y = acc[i][1] + cv.y;
        o.z = acc[i][2] + cv.z; o.w = acc[i][3] + cv.w;
        *(float4*)(pre + (size_t)row * kHID + col) = o;
    }
}

__device__ __forceinline__ float softplus_f(float x) {
    return fmaxf(x, 0.f) + __logf(1.f + __expf(-fabsf(x)));
}

__global__ __launch_bounds__(256) void classify(const float* __restrict__ pre,
                                                const float* __restrict__ U,
                                                const float* __restrict__ dvec,
                                                float* __restrict__ out) {
    __shared__ float preS[4][kHID];
    __shared__ float Fs[4][kCLS];
    const int tid = threadIdx.x;
    const int lane = tid & 63, wave = tid >> 6;
    const int b0 = blockIdx.x * 4;
    const float4* src = (const float4*)(pre + (size_t)b0 * kHID);
    float4* dst = (float4*)preS;
    for (int i = tid; i < kHID; i += 256) dst[i] = src[i];
    __syncthreads();
    for (int yi = 0; yi < 16; ++yi) {
        const int y = (wave << 4) + yi;
        const float* Uy = U + (size_t)y * kHID;
        float a0 = 0.f, a1 = 0.f, a2 = 0.f, a3 = 0.f;
#pragma unroll
        for (int it = 0; it < kHID / 64; ++it) {
            const int j = lane + (it << 6);
            const float u = Uy[j];
            a0 += softplus_f(preS[0][j] + u);
            a1 += softplus_f(preS[1][j] + u);
            a2 += softplus_f(preS[2][j] + u);
            a3 += softplus_f(preS[3][j] + u);
        }
        double d0 = a0, d1 = a1, d2 = a2, d3 = a3;
#pragma unroll
        for (int off = 32; off; off >>= 1) {
            d0 += __shfl_xor(d0, off); d1 += __shfl_xor(d1, off);
            d2 += __shfl_xor(d2, off); d3 += __shfl_xor(d3, off);
        }
        if (lane == 0) {
            const float dy = dvec[y];
            Fs[0][y] = (float)d0 + dy; Fs[1][y] = (float)d1 + dy;
            Fs[2][y] = (float)d2 + dy; Fs[3][y] = (float)d3 + dy;
        }
    }
    __syncthreads();
    const float F = Fs[wave][lane];
    float m = F; int mi = lane;
#pragma unroll
    for (int off = 32; off; off >>= 1) {
        const float om = __shfl_xor(m, off);
        const int oi = __shfl_xor(mi, off);
        if (om > m || (om == m && oi < mi)) { m = om; mi = oi; }
    }
    const float e = __expf(F - m);
    float s = e;
#pragma unroll
    for (int off = 32; off; off >>= 1) s += __shfl_xor(s, off);
    const int row = b0 + wave;
    out[(size_t)row * kCLS + lane] = e / s;
    out[(size_t)kB * kCLS + (size_t)row * kCLS + lane] = (lane == mi) ? 1.0f : 0.0f;
}

extern "C" void kernel_launch(void* const* d_in, const int* in_sizes, int n_in,
                              void* d_out, int out_size, void* d_ws, size_t ws_size,
                              hipStream_t stream) {
    const float* v = (const float*)d_in[0];
    const float* W = (const float*)d_in[1];
    const float* c = (const float*)d_in[2];
    const float* d = (const float*)d_in[3];
    const float* U = (const float*)d_in[4];
    float* out = (float*)d_out;
    char* ws = (char*)d_ws;

    // ws layout: vh 8MB | vl 8MB | Wt_h 4MB | Wt_l 4MB | Utp 256KB | Fpart 8MB | ctrs 256B
    const size_t need  = 33816576;
    const size_t need2 = need + 256;
    if (ws_size >= need) {
        unsigned short* vh  = (unsigned short*)(ws);
        unsigned short* vl  = (unsigned short*)(ws + 8388608);
        unsigned short* wth = (unsigned short*)(ws + 16777216);
        unsigned short* wtl = (unsigned short*)(ws + 20971520);
        float* Utp   = (float*)(ws + 25165824);
        float* Fpart = (float*)(ws + 25427968);
        int* ctrs    = (ws_size >= need2) ? (int*)(ws + need) : nullptr;
        prep_all<<<6401, 256, 0, stream>>>(v, W, U, vh, vl, wth, wtl, Utp, ctrs);
        gemm_fused<<<dim3(kHID / 64, kB / 64), 256, 0, stream>>>(vh, vl, wth, wtl, c, Utp,
                                                                 d, Fpart, ctrs, out);
        if (!ctrs) softmax_final<<<kB / 4, 256, 0, stream>>>(Fpart, d, out);
    } else {
        float* pre = (float*)ws;
        gemm_vw<<<dim3(kHID / BN, kB / BM), 256, 0, stream>>>(v, W, c, pre);
        classify<<<kB / 4, 256, 0, stream>>>(pre, U, d, out);
    }
}

// Round 7
// 131.549 us; speedup vs baseline: 1.6268x; 1.6268x over previous
//
#include <hip/hip_runtime.h>

// Problem sizes (fixed by the reference)
constexpr int kB    = 2048;  // batch
constexpr int kVIS  = 2048;  // visible units (GEMM K)
constexpr int kHID  = 1024;  // hidden units (GEMM N)
constexpr int kCLS  = 64;    // classes
constexpr float kLog2e = 1.4426950408889634f;

typedef __attribute__((ext_vector_type(8))) short bf16x8;
typedef __attribute__((ext_vector_type(4))) float f32x4;
typedef __attribute__((ext_vector_type(2))) float f32x2;

typedef __attribute__((address_space(3))) unsigned       as3_u32;
typedef __attribute__((address_space(1))) const unsigned as1_u32;

__device__ __forceinline__ void g2lds16(const void* g, void* l) {
    // async global->LDS DMA, 16 B per lane; LDS dest is wave-base + lane*16
    __builtin_amdgcn_global_load_lds((as1_u32*)g, (as3_u32*)l, 16, 0, 0);
}

__device__ __forceinline__ unsigned short f2bf(float x) {
    unsigned u = __float_as_uint(x);
    u += 0x7fffu + ((u >> 16) & 1u);
    return (unsigned short)(u >> 16);
}
__device__ __forceinline__ float bf2f(unsigned short h) {
    return __uint_as_float(((unsigned)h) << 16);
}

// ---------------- Prep (merged): split v, split+transpose W, pack+scale U ----------------
// blocks [0,4096): split_v ; [4096,6144): split_w_t ; [6144,6400): pack_u
__global__ __launch_bounds__(256) void prep_all(const float* __restrict__ v,
                                                const float* __restrict__ W,
                                                const float* __restrict__ U,
                                                unsigned short* __restrict__ vh,
                                                unsigned short* __restrict__ vl,
                                                unsigned short* __restrict__ wth,
                                                unsigned short* __restrict__ wtl,
                                                float* __restrict__ Utp) {
    __shared__ float T[32][33];
    const int bx = blockIdx.x;
    if (bx < 4096) {
        const int i = (bx * 256 + threadIdx.x) * 4;
        const float4 xv = *(const float4*)(v + i);
        ushort4 h, l;
        h.x = f2bf(xv.x); l.x = f2bf(xv.x - bf2f(h.x));
        h.y = f2bf(xv.y); l.y = f2bf(xv.y - bf2f(h.y));
        h.z = f2bf(xv.z); l.z = f2bf(xv.z - bf2f(h.z));
        h.w = f2bf(xv.w); l.w = f2bf(xv.w - bf2f(h.w));
        *(ushort4*)(vh + i) = h;
        *(ushort4*)(vl + i) = l;
    } else if (bx < 6144) {
        const int b = bx - 4096;
        const int n0 = (b & 31) * 32, k0 = (b >> 5) * 32;
        const int c = threadIdx.x & 31, r0 = threadIdx.x >> 5;
#pragma unroll
        for (int p = 0; p < 4; ++p) {
            const int r = r0 + p * 8;
            T[r][c] = W[(size_t)(k0 + r) * kHID + n0 + c];
        }
        __syncthreads();
#pragma unroll
        for (int p = 0; p < 4; ++p) {
            const int rr = r0 + p * 8;          // n offset
            const float x = T[c][rr];           // = W[k0+c][n0+rr]
            const unsigned short h = f2bf(x);
            const unsigned short l = f2bf(x - bf2f(h));
            const size_t o = (size_t)(n0 + rr) * kVIS + k0 + c;
            wth[o] = h;
            wtl[o] = l;
        }
    } else {
        const int id = (bx - 6144) * 256 + threadIdx.x;  // 0..65535
        const int j = id >> 6, y = id & 63;
        // packed: Utp[((j>>2)*64 + y)*4 + (j&3)]  ->  one dwordx4 per (j-quad, class)
        Utp[(((j >> 2) * kCLS + y) << 2) + (j & 3)] = U[(size_t)y * kHID + j] * kLog2e;
    }
}

// ---------------- Fused kernel: split-bf16 MFMA GEMM + softplus partial-F epilogue ------
// R4 main-loop structure (best measured): 64x64 tile, 4 waves (32x32 quadrants, 2x2 of
// mfma_f32_16x16x32_bf16, 3 products), both operands DMA-staged per K=64 slab with
// XOR-swizzled octets (LDK=64, conflict-free), 2 barriers/slab, 32 KB LDS.
// 1D grid + XCD swizzle: bid&7 selects XCD-group; all 16 n-tiles of an m-stripe land on
// one XCD so the A-stripe is fetched into that XCD's L2 once.
// Epilogue: ps[64][68] overlay, packed-f32 softplus, Utp packed dwordx4 (L2-hot).
__global__ __launch_bounds__(256) void gemm_fused(const unsigned short* __restrict__ vh,
                                                  const unsigned short* __restrict__ vl,
                                                  const unsigned short* __restrict__ wth,
                                                  const unsigned short* __restrict__ wtl,
                                                  const float* __restrict__ cvec,
                                                  const float* __restrict__ Utp,
                                                  float* __restrict__ Fpart) {
    __shared__ __align__(16) union SMem {
        unsigned short stage[4][64 * 64];   // Ah, Al, Bh, Bl  (32768 B)
        float ps[64][68];                   // 17408 B, overlays stage
    } smem;
    unsigned short* Ah = smem.stage[0];
    unsigned short* Al = smem.stage[1];
    unsigned short* Bh = smem.stage[2];
    unsigned short* Bl = smem.stage[3];

    const int tid = threadIdx.x;
    const int lane = tid & 63, wave = tid >> 6;

    // XCD-aware decomposition of the 1D grid (512 blocks, 32 m-stripes x 16 n-tiles):
    // xcd-group = bid&7 owns m-stripes [4*(bid&7), +4); within group, 16 n-tiles x 4 m.
    const int bid = blockIdx.x;
    const int idx = bid >> 3;                 // 0..63
    const int mstripe = ((bid & 7) << 2) + (idx >> 4);  // 0..31
    const int ncol = idx & 15;                // 0..15
    const int m0 = mstripe * 64, n0 = ncol * 64;
    const int wm = (wave >> 1) * 32, wn = (wave & 1) * 32;

    // staging: thread covers rows r0 and r0+32; k-octet XOR-swizzled on global side
    const int r0 = tid >> 3, r1 = r0 + 32;
    const int oc = (((tid & 7) ^ ((tid >> 3) & 7)) << 3);   // global k-octet offset (elems)
    const size_t ga0 = (size_t)(m0 + r0) * kVIS + oc;
    const size_t ga1 = (size_t)(m0 + r1) * kVIS + oc;
    const size_t gb0 = (size_t)(n0 + r0) * kVIS + oc;
    const size_t gb1 = (size_t)(n0 + r1) * kVIS + oc;
    const int l0 = (r0 << 6) + ((tid & 7) << 3);            // physical LDS slot (elems)
    const int l1 = (r1 << 6) + ((tid & 7) << 3);

    // fragment addressing: A[m=lane&15][k], row-major LDK=64, swizzled octet
    const int fm = lane & 15, fq = lane >> 4;
    const int rx = fm & 7;
    const int a0r = (wm + fm) << 6,  a1r = (wm + 16 + fm) << 6;
    const int b0r = (wn + fm) << 6,  b1r = (wn + 16 + fm) << 6;

    f32x4 acc[2][2] = {};

    for (int k0 = 0; k0 < kVIS; k0 += 64) {
        __syncthreads();  // prior compute done reading LDS
        g2lds16(vh + ga0 + k0, Ah + l0);
        g2lds16(vh + ga1 + k0, Ah + l1);
        g2lds16(vl + ga0 + k0, Al + l0);
        g2lds16(vl + ga1 + k0, Al + l1);
        g2lds16(wth + gb0 + k0, Bh + l0);
        g2lds16(wth + gb1 + k0, Bh + l1);
        g2lds16(wtl + gb0 + k0, Bl + l0);
        g2lds16(wtl + gb1 + k0, Bl + l1);
        __syncthreads();  // drains vmcnt -> staged data visible
#pragma unroll
        for (int kk = 0; kk < 64; kk += 32) {
            const int p = (((kk >> 3) + fq) ^ rx) << 3;     // swizzled octet (elems)
            const bf16x8 ah0 = *(const bf16x8*)(Ah + a0r + p);
            const bf16x8 ah1 = *(const bf16x8*)(Ah + a1r + p);
            const bf16x8 al0 = *(const bf16x8*)(Al + a0r + p);
            const bf16x8 al1 = *(const bf16x8*)(Al + a1r + p);
            const bf16x8 bh0 = *(const bf16x8*)(Bh + b0r + p);
            const bf16x8 bh1 = *(const bf16x8*)(Bh + b1r + p);
            const bf16x8 bl0 = *(const bf16x8*)(Bl + b0r + p);
            const bf16x8 bl1 = *(const bf16x8*)(Bl + b1r + p);
            acc[0][0] = __builtin_amdgcn_mfma_f32_16x16x32_bf16(ah0, bh0, acc[0][0], 0, 0, 0);
            acc[0][0] = __builtin_amdgcn_mfma_f32_16x16x32_bf16(ah0, bl0, acc[0][0], 0, 0, 0);
            acc[0][0] = __builtin_amdgcn_mfma_f32_16x16x32_bf16(al0, bh0, acc[0][0], 0, 0, 0);
            acc[0][1] = __builtin_amdgcn_mfma_f32_16x16x32_bf16(ah0, bh1, acc[0][1], 0, 0, 0);
            acc[0][1] = __builtin_amdgcn_mfma_f32_16x16x32_bf16(ah0, bl1, acc[0][1], 0, 0, 0);
            acc[0][1] = __builtin_amdgcn_mfma_f32_16x16x32_bf16(al0, bh1, acc[0][1], 0, 0, 0);
            acc[1][0] = __builtin_amdgcn_mfma_f32_16x16x32_bf16(ah1, bh0, acc[1][0], 0, 0, 0);
            acc[1][0] = __builtin_amdgcn_mfma_f32_16x16x32_bf16(ah1, bl0, acc[1][0], 0, 0, 0);
            acc[1][0] = __builtin_amdgcn_mfma_f32_16x16x32_bf16(al1, bh0, acc[1][0], 0, 0, 0);
            acc[1][1] = __builtin_amdgcn_mfma_f32_16x16x32_bf16(ah1, bh1, acc[1][1], 0, 0, 0);
            acc[1][1] = __builtin_amdgcn_mfma_f32_16x16x32_bf16(ah1, bl1, acc[1][1], 0, 0, 0);
            acc[1][1] = __builtin_amdgcn_mfma_f32_16x16x32_bf16(al1, bh1, acc[1][1], 0, 0, 0);
        }
    }

    // ---- epilogue phase 1: pre-tile -> ps (log2 domain, +c); 2-way writes (stride 68)
    __syncthreads();  // all waves done reading stage LDS (union overlay)
#pragma unroll
    for (int j = 0; j < 2; ++j) {
        const int col = wn + j * 16 + fm;              // local hid col 0..63
        const float cv = cvec[n0 + col];
#pragma unroll
        for (int i = 0; i < 2; ++i) {
            const int rbase = wm + i * 16 + fq * 4;    // local row
#pragma unroll
            for (int r = 0; r < 4; ++r)
                smem.ps[rbase + r][col] = (acc[i][j][r] + cv) * kLog2e;
        }
    }
    __syncthreads();

    // ---- epilogue phase 2: packed-f32 softplus; wave owns rows [wave*16,+16), lane=class
    const int q0 = (n0 >> 2);
    f32x2 relu2[16], prod2[16];
#pragma unroll
    for (int rr = 0; rr < 16; ++rr) { relu2[rr] = (f32x2)(0.f); prod2[rr] = (f32x2)(1.f); }

    const f32x2 zero2 = (f32x2)(0.f);
    for (int jc = 0; jc < 64; jc += 8) {
        const float4 ua = ((const float4*)Utp)[(q0 + (jc >> 2) + 0) * kCLS + lane];
        const float4 ub = ((const float4*)Utp)[(q0 + (jc >> 2) + 1) * kCLS + lane];
        const f32x2 u01 = {ua.x, ua.y}, u23 = {ua.z, ua.w};
        const f32x2 u45 = {ub.x, ub.y}, u67 = {ub.z, ub.w};
#pragma unroll
        for (int rr = 0; rr < 16; ++rr) {
            const float4 p0 = *(const float4*)&smem.ps[wave * 16 + rr][jc];      // broadcast
            const float4 p1 = *(const float4*)&smem.ps[wave * 16 + rr][jc + 4];  // broadcast
            f32x2 tp[4];
            tp[0] = (f32x2){p0.x, p0.y} + u01;
            tp[1] = (f32x2){p0.z, p0.w} + u23;
            tp[2] = (f32x2){p1.x, p1.y} + u45;
            tp[3] = (f32x2){p1.z, p1.w} + u67;
#pragma unroll
            for (int g = 0; g < 4; ++g) {
                const f32x2 t = tp[g];
                f32x2 e;
                e.x = __builtin_amdgcn_exp2f(-__builtin_fabsf(t.x));
                e.y = __builtin_amdgcn_exp2f(-__builtin_fabsf(t.y));
                prod2[rr] = __builtin_elementwise_fma(prod2[rr], e, prod2[rr]);  // *= (1+e), <=2^32/comp
                relu2[rr] += __builtin_elementwise_max(t, zero2);
            }
        }
    }
#pragma unroll
    for (int rr = 0; rr < 16; ++rr) {
        const float contrib = relu2[rr].x + relu2[rr].y +
                              __builtin_amdgcn_logf(prod2[rr].x * prod2[rr].y);  // log2 domain
        Fpart[((size_t)ncol * kB + m0 + wave * 16 + rr) * kCLS + lane] = contrib;
    }
}

// ---------------- Final: sum 16 partials (double), softmax, argmax, one-hot ------------
__global__ __launch_bounds__(256) void softmax_final(const float* __restrict__ Fpart,
                                                     const float* __restrict__ dvec,
                                                     float* __restrict__ out) {
    const int tid = threadIdx.x;
    const int lane = tid & 63, wave = tid >> 6;
    const int row = blockIdx.x * 4 + wave;
    double s = 0.0;
#pragma unroll
    for (int k = 0; k < kHID / 64; ++k)
        s += (double)Fpart[((size_t)k * kB + row) * kCLS + lane];
    const float G = (float)s + dvec[lane] * kLog2e;  // log2-domain logit

    float m = G;
    int mi = lane;
#pragma unroll
    for (int off = 32; off; off >>= 1) {
        const float om = __shfl_xor(m, off);
        const int   oi = __shfl_xor(mi, off);
        if (om > m || (om == m && oi < mi)) { m = om; mi = oi; }  // first-index tie-break
    }
    const float e2 = __builtin_amdgcn_exp2f(G - m);
    float ssum = e2;
#pragma unroll
    for (int off = 32; off; off >>= 1) ssum += __shfl_xor(ssum, off);
    out[(size_t)row * kCLS + lane] = e2 / ssum;
    out[(size_t)kB * kCLS + (size_t)row * kCLS + lane] = (lane == mi) ? 1.0f : 0.0f;
}

// ================= Fallback (round-1, known-passing) if ws is too small =================
constexpr int BM = 64, BN = 64, BK = 16;

__global__ __launch_bounds__(256) void gemm_vw(const float* __restrict__ V,
                                               const float* __restrict__ Wm,
                                               const float* __restrict__ cvec,
                                               float* __restrict__ pre) {
    __shared__ float As[BK][BM + 4];
    __shared__ float Bs[BK][BN + 4];
    const int tid = threadIdx.x;
    const int tx = tid & 15, ty = tid >> 4;
    const int m0 = blockIdx.y * BM, n0 = blockIdx.x * BN;
    const int arow = tid >> 2, acol = (tid & 3) << 2;
    const int brow = tid >> 4, bcol = (tid & 15) << 2;
    const float* vptr = V + (size_t)(m0 + arow) * kVIS + acol;
    const float* wptr = Wm + (size_t)brow * kHID + n0 + bcol;
    float acc[4][4] = {};
    for (int k0 = 0; k0 < kVIS; k0 += BK) {
        const float4 a4 = *(const float4*)(vptr + k0);
        const float4 b4 = *(const float4*)(wptr + (size_t)k0 * kHID);
        __syncthreads();
        As[acol + 0][arow] = a4.x; As[acol + 1][arow] = a4.y;
        As[acol + 2][arow] = a4.z; As[acol + 3][arow] = a4.w;
        *(float4*)&Bs[brow][bcol] = b4;
        __syncthreads();
#pragma unroll
        for (int k = 0; k < BK; ++k) {
            const float4 av = *(const float4*)&As[k][ty << 2];
            const float4 bv = *(const float4*)&Bs[k][tx << 2];
            const float a[4] = {av.x, av.y, av.z, av.w};
            const float b[4] = {bv.x, bv.y, bv.z, bv.w};
#pragma unroll
            for (int i = 0; i < 4; ++i)
#pragma unroll
                for (int j = 0; j < 4; ++j) acc[i][j] += a[i] * b[j];
        }
    }
#pragma unroll
    for (int i = 0; i < 4; ++i) {
        const int row = m0 + (ty << 2) + i;
        const int col = n0 + (tx << 2);
        const float4 cv = *(const float4*)(cvec + col);
        float4 o;
        o.x = acc[i][0] + cv.x; o.y = acc[i][1] + cv.y;
        o.z = acc[i][2] + cv.z; o.w = acc[i][3] + cv.w;
        *(float4*)(pre + (size_t)row * kHID + col) = o;
    }
}

__device__ __forceinline__ float softplus_f(float x) {
    return fmaxf(x, 0.f) + __logf(1.f + __expf(-fabsf(x)));
}

__global__ __launch_bounds__(256) void classify(const float* __restrict__ pre,
                                                const float* __restrict__ U,
                                                const float* __restrict__ dvec,
                                                float* __restrict__ out) {
    __shared__ float preS[4][kHID];
    __shared__ float Fs[4][kCLS];
    const int tid = threadIdx.x;
    const int lane = tid & 63, wave = tid >> 6;
    const int b0 = blockIdx.x * 4;
    const float4* src = (const float4*)(pre + (size_t)b0 * kHID);
    float4* dst = (float4*)preS;
    for (int i = tid; i < kHID; i += 256) dst[i] = src[i];
    __syncthreads();
    for (int yi = 0; yi < 16; ++yi) {
        const int y = (wave << 4) + yi;
        const float* Uy = U + (size_t)y * kHID;
        float a0 = 0.f, a1 = 0.f, a2 = 0.f, a3 = 0.f;
#pragma unroll
        for (int it = 0; it < kHID / 64; ++it) {
            const int j = lane + (it << 6);
            const float u = Uy[j];
            a0 += softplus_f(preS[0][j] + u);
            a1 += softplus_f(preS[1][j] + u);
            a2 += softplus_f(preS[2][j] + u);
            a3 += softplus_f(preS[3][j] + u);
        }
        double d0 = a0, d1 = a1, d2 = a2, d3 = a3;
#pragma unroll
        for (int off = 32; off; off >>= 1) {
            d0 += __shfl_xor(d0, off); d1 += __shfl_xor(d1, off);
            d2 += __shfl_xor(d2, off); d3 += __shfl_xor(d3, off);
        }
        if (lane == 0) {
            const float dy = dvec[y];
            Fs[0][y] = (float)d0 + dy; Fs[1][y] = (float)d1 + dy;
            Fs[2][y] = (float)d2 + dy; Fs[3][y] = (float)d3 + dy;
        }
    }
    __syncthreads();
    const float F = Fs[wave][lane];
    float m = F; int mi = lane;
#pragma unroll
    for (int off = 32; off; off >>= 1) {
        const float om = __shfl_xor(m, off);
        const int oi = __shfl_xor(mi, off);
        if (om > m || (om == m && oi < mi)) { m = om; mi = oi; }
    }
    const float e = __expf(F - m);
    float s = e;
#pragma unroll
    for (int off = 32; off; off >>= 1) s += __shfl_xor(s, off);
    const int row = b0 + wave;
    out[(size_t)row * kCLS + lane] = e / s;
    out[(size_t)kB * kCLS + (size_t)row * kCLS + lane] = (lane == mi) ? 1.0f : 0.0f;
}

extern "C" void kernel_launch(void* const* d_in, const int* in_sizes, int n_in,
                              void* d_out, int out_size, void* d_ws, size_t ws_size,
                              hipStream_t stream) {
    const float* v = (const float*)d_in[0];
    const float* W = (const float*)d_in[1];
    const float* c = (const float*)d_in[2];
    const float* d = (const float*)d_in[3];
    const float* U = (const float*)d_in[4];
    float* out = (float*)d_out;
    char* ws = (char*)d_ws;

    // ws layout: vh 8MB | vl 8MB | Wt_h 4MB | Wt_l 4MB | Utp 256KB | Fpart 8MB
    const size_t need = 33816576;
    if (ws_size >= need) {
        unsigned short* vh  = (unsigned short*)(ws);
        unsigned short* vl  = (unsigned short*)(ws + 8388608);
        unsigned short* wth = (unsigned short*)(ws + 16777216);
        unsigned short* wtl = (unsigned short*)(ws + 20971520);
        float* Utp   = (float*)(ws + 25165824);
        float* Fpart = (float*)(ws + 25427968);
        prep_all<<<6400, 256, 0, stream>>>(v, W, U, vh, vl, wth, wtl, Utp);
        gemm_fused<<<512, 256, 0, stream>>>(vh, vl, wth, wtl, c, Utp, Fpart);
        softmax_final<<<kB / 4, 256, 0, stream>>>(Fpart, d, out);
    } else {
        float* pre = (float*)ws;
        gemm_vw<<<dim3(kHID / BN, kB / BM), 256, 0, stream>>>(v, W, c, pre);
        classify<<<kB / 4, 256, 0, stream>>>(pre, U, d, out);
    }
}

// Round 8
// 128.973 us; speedup vs baseline: 1.6593x; 1.0200x over previous
//
#include <hip/hip_runtime.h>

// Problem sizes (fixed by the reference)
constexpr int kB    = 2048;  // batch
constexpr int kVIS  = 2048;  // visible units (GEMM K)
constexpr int kHID  = 1024;  // hidden units (GEMM N)
constexpr int kCLS  = 64;    // classes
constexpr float kLog2e = 1.4426950408889634f;

typedef __attribute__((ext_vector_type(8))) short bf16x8;
typedef __attribute__((ext_vector_type(4))) float f32x4;
typedef __attribute__((ext_vector_type(2))) float f32x2;

typedef __attribute__((address_space(3))) unsigned       as3_u32;
typedef __attribute__((address_space(1))) const unsigned as1_u32;

__device__ __forceinline__ void g2lds16(const void* g, void* l) {
    // async global->LDS DMA, 16 B per lane; LDS dest is wave-base + lane*16
    __builtin_amdgcn_global_load_lds((as1_u32*)g, (as3_u32*)l, 16, 0, 0);
}

__device__ __forceinline__ unsigned short f2bf(float x) {
    unsigned u = __float_as_uint(x);
    u += 0x7fffu + ((u >> 16) & 1u);
    return (unsigned short)(u >> 16);
}
__device__ __forceinline__ float bf2f(unsigned short h) {
    return __uint_as_float(((unsigned)h) << 16);
}

// ---------------- Prep (merged): split v, split+transpose W, pack+scale U ----------------
// blocks [0,4096): split_v ; [4096,6144): split_w_t ; [6144,6400): pack_u
__global__ __launch_bounds__(256) void prep_all(const float* __restrict__ v,
                                                const float* __restrict__ W,
                                                const float* __restrict__ U,
                                                unsigned short* __restrict__ vh,
                                                unsigned short* __restrict__ vl,
                                                unsigned short* __restrict__ wth,
                                                unsigned short* __restrict__ wtl,
                                                float* __restrict__ Utp) {
    __shared__ float T[32][33];
    const int bx = blockIdx.x;
    if (bx < 4096) {
        const int i = (bx * 256 + threadIdx.x) * 4;
        const float4 xv = *(const float4*)(v + i);
        ushort4 h, l;
        h.x = f2bf(xv.x); l.x = f2bf(xv.x - bf2f(h.x));
        h.y = f2bf(xv.y); l.y = f2bf(xv.y - bf2f(h.y));
        h.z = f2bf(xv.z); l.z = f2bf(xv.z - bf2f(h.z));
        h.w = f2bf(xv.w); l.w = f2bf(xv.w - bf2f(h.w));
        *(ushort4*)(vh + i) = h;
        *(ushort4*)(vl + i) = l;
    } else if (bx < 6144) {
        const int b = bx - 4096;
        const int n0 = (b & 31) * 32, k0 = (b >> 5) * 32;
        const int c = threadIdx.x & 31, r0 = threadIdx.x >> 5;
#pragma unroll
        for (int p = 0; p < 4; ++p) {
            const int r = r0 + p * 8;
            T[r][c] = W[(size_t)(k0 + r) * kHID + n0 + c];
        }
        __syncthreads();
#pragma unroll
        for (int p = 0; p < 4; ++p) {
            const int rr = r0 + p * 8;          // n offset
            const float x = T[c][rr];           // = W[k0+c][n0+rr]
            const unsigned short h = f2bf(x);
            const unsigned short l = f2bf(x - bf2f(h));
            const size_t o = (size_t)(n0 + rr) * kVIS + k0 + c;
            wth[o] = h;
            wtl[o] = l;
        }
    } else {
        const int id = (bx - 6144) * 256 + threadIdx.x;  // 0..65535
        const int j = id >> 6, y = id & 63;
        // packed: Utp[((j>>2)*64 + y)*4 + (j&3)]  ->  one dwordx4 per (j-quad, class)
        Utp[(((j >> 2) * kCLS + y) << 2) + (j & 3)] = U[(size_t)y * kHID + j] * kLog2e;
    }
}

// ---------------- Fused kernel: split-bf16 MFMA GEMM + softplus partial-F epilogue ------
// 64x64 tile, 4 waves (32x32 quadrants, 2x2 of mfma_f32_16x16x32_bf16, 3 products).
// BOTH operands double-buffered in exactly 64 KiB LDS (2 x 32 KB, XOR-swizzled octets):
// one barrier per K=64 slab; DMA for slab k+1 flies during slab k's compute, so the
// barrier's vmcnt(0) drain finds it already complete (R4's issue->drain convoy removed).
// 64 KiB exactly => 2 blocks/CU within the 128 KiB schedulable budget (R5's 66048-B
// block fell to 1 block/CU -- do NOT add any other __shared__).
// 1D grid + XCD swizzle (R7): bid&7 = XCD-group; A-stripe fetched once per XCD L2.
// Epilogue: ps[64][68] overlay, packed-f32 softplus, Utp packed dwordx4 (L2-hot).
__global__ __launch_bounds__(256) void gemm_fused(const unsigned short* __restrict__ vh,
                                                  const unsigned short* __restrict__ vl,
                                                  const unsigned short* __restrict__ wth,
                                                  const unsigned short* __restrict__ wtl,
                                                  const float* __restrict__ cvec,
                                                  const float* __restrict__ Utp,
                                                  float* __restrict__ Fpart) {
    __shared__ __align__(16) union SMem {
        unsigned short stage[2][4][64 * 64];  // [buf][Ah,Al,Bh,Bl][row][k]  = 65536 B
        float ps[64][68];                     // 17408 B, overlays stage
    } smem;

    const int tid = threadIdx.x;
    const int lane = tid & 63, wave = tid >> 6;

    // XCD-aware decomposition of the 1D grid (512 blocks, 32 m-stripes x 16 n-tiles)
    const int bid = blockIdx.x;
    const int idx = bid >> 3;                           // 0..63
    const int mstripe = ((bid & 7) << 2) + (idx >> 4);  // 0..31
    const int ncol = idx & 15;                          // 0..15
    const int m0 = mstripe * 64, n0 = ncol * 64;
    const int wm = (wave >> 1) * 32, wn = (wave & 1) * 32;

    // staging: thread covers rows r0 and r0+32; k-octet XOR-swizzled on global side
    const int r0 = tid >> 3, r1 = r0 + 32;
    const int oc = (((tid & 7) ^ ((tid >> 3) & 7)) << 3);   // global k-octet offset (elems)
    const size_t ga0 = (size_t)(m0 + r0) * kVIS + oc;
    const size_t ga1 = (size_t)(m0 + r1) * kVIS + oc;
    const size_t gb0 = (size_t)(n0 + r0) * kVIS + oc;
    const size_t gb1 = (size_t)(n0 + r1) * kVIS + oc;
    const int l0 = (r0 << 6) + ((tid & 7) << 3);            // physical LDS slot (elems)
    const int l1 = (r1 << 6) + ((tid & 7) << 3);

    // fragment addressing: A[m=lane&15][k], row-major LDK=64, swizzled octet
    const int fm = lane & 15, fq = lane >> 4;
    const int rx = fm & 7;
    const int a0r = (wm + fm) << 6,  a1r = (wm + 16 + fm) << 6;
    const int b0r = (wn + fm) << 6,  b1r = (wn + 16 + fm) << 6;

    f32x4 acc[2][2] = {};

    // prime: DMA slab 0 into buffer 0
    {
        unsigned short* Ah = smem.stage[0][0];
        unsigned short* Al = smem.stage[0][1];
        unsigned short* Bh = smem.stage[0][2];
        unsigned short* Bl = smem.stage[0][3];
        g2lds16(vh + ga0, Ah + l0);  g2lds16(vh + ga1, Ah + l1);
        g2lds16(vl + ga0, Al + l0);  g2lds16(vl + ga1, Al + l1);
        g2lds16(wth + gb0, Bh + l0); g2lds16(wth + gb1, Bh + l1);
        g2lds16(wtl + gb0, Bl + l0); g2lds16(wtl + gb1, Bl + l1);
    }
    __syncthreads();  // drain prime DMA

    int cur = 0;
    for (int k0 = 0; k0 < kVIS; k0 += 64) {
        // prefetch next slab into the idle buffer (flies during this slab's compute)
        if (k0 + 64 < kVIS) {
            unsigned short* Ah = smem.stage[cur ^ 1][0];
            unsigned short* Al = smem.stage[cur ^ 1][1];
            unsigned short* Bh = smem.stage[cur ^ 1][2];
            unsigned short* Bl = smem.stage[cur ^ 1][3];
            const int ko = k0 + 64;
            g2lds16(vh + ga0 + ko, Ah + l0);  g2lds16(vh + ga1 + ko, Ah + l1);
            g2lds16(vl + ga0 + ko, Al + l0);  g2lds16(vl + ga1 + ko, Al + l1);
            g2lds16(wth + gb0 + ko, Bh + l0); g2lds16(wth + gb1 + ko, Bh + l1);
            g2lds16(wtl + gb0 + ko, Bl + l0); g2lds16(wtl + gb1 + ko, Bl + l1);
        }
        const unsigned short* Ah = smem.stage[cur][0];
        const unsigned short* Al = smem.stage[cur][1];
        const unsigned short* Bh = smem.stage[cur][2];
        const unsigned short* Bl = smem.stage[cur][3];
#pragma unroll
        for (int kk = 0; kk < 64; kk += 32) {
            const int p = (((kk >> 3) + fq) ^ rx) << 3;     // swizzled octet (elems)
            const bf16x8 ah0 = *(const bf16x8*)(Ah + a0r + p);
            const bf16x8 ah1 = *(const bf16x8*)(Ah + a1r + p);
            const bf16x8 al0 = *(const bf16x8*)(Al + a0r + p);
            const bf16x8 al1 = *(const bf16x8*)(Al + a1r + p);
            const bf16x8 bh0 = *(const bf16x8*)(Bh + b0r + p);
            const bf16x8 bh1 = *(const bf16x8*)(Bh + b1r + p);
            const bf16x8 bl0 = *(const bf16x8*)(Bl + b0r + p);
            const bf16x8 bl1 = *(const bf16x8*)(Bl + b1r + p);
            acc[0][0] = __builtin_amdgcn_mfma_f32_16x16x32_bf16(ah0, bh0, acc[0][0], 0, 0, 0);
            acc[0][0] = __builtin_amdgcn_mfma_f32_16x16x32_bf16(ah0, bl0, acc[0][0], 0, 0, 0);
            acc[0][0] = __builtin_amdgcn_mfma_f32_16x16x32_bf16(al0, bh0, acc[0][0], 0, 0, 0);
            acc[0][1] = __builtin_amdgcn_mfma_f32_16x16x32_bf16(ah0, bh1, acc[0][1], 0, 0, 0);
            acc[0][1] = __builtin_amdgcn_mfma_f32_16x16x32_bf16(ah0, bl1, acc[0][1], 0, 0, 0);
            acc[0][1] = __builtin_amdgcn_mfma_f32_16x16x32_bf16(al0, bh1, acc[0][1], 0, 0, 0);
            acc[1][0] = __builtin_amdgcn_mfma_f32_16x16x32_bf16(ah1, bh0, acc[1][0], 0, 0, 0);
            acc[1][0] = __builtin_amdgcn_mfma_f32_16x16x32_bf16(ah1, bl0, acc[1][0], 0, 0, 0);
            acc[1][0] = __builtin_amdgcn_mfma_f32_16x16x32_bf16(al1, bh0, acc[1][0], 0, 0, 0);
            acc[1][1] = __builtin_amdgcn_mfma_f32_16x16x32_bf16(ah1, bh1, acc[1][1], 0, 0, 0);
            acc[1][1] = __builtin_amdgcn_mfma_f32_16x16x32_bf16(ah1, bl1, acc[1][1], 0, 0, 0);
            acc[1][1] = __builtin_amdgcn_mfma_f32_16x16x32_bf16(al1, bh1, acc[1][1], 0, 0, 0);
        }
        // single barrier per slab: waves done reading cur; prefetch DMA drained (already
        // complete -- it had the whole compute phase to fly)
        __syncthreads();
        cur ^= 1;
    }

    // ---- epilogue phase 1: pre-tile -> ps (log2 domain, +c); 2-way writes (stride 68)
    // (final loop barrier guarantees all stage reads are done before the overlay write)
#pragma unroll
    for (int j = 0; j < 2; ++j) {
        const int col = wn + j * 16 + fm;              // local hid col 0..63
        const float cv = cvec[n0 + col];
#pragma unroll
        for (int i = 0; i < 2; ++i) {
            const int rbase = wm + i * 16 + fq * 4;    // local row
#pragma unroll
            for (int r = 0; r < 4; ++r)
                smem.ps[rbase + r][col] = (acc[i][j][r] + cv) * kLog2e;
        }
    }
    __syncthreads();

    // ---- epilogue phase 2: packed-f32 softplus; wave owns rows [wave*16,+16), lane=class
    const int q0 = (n0 >> 2);
    f32x2 relu2[16], prod2[16];
#pragma unroll
    for (int rr = 0; rr < 16; ++rr) { relu2[rr] = (f32x2)(0.f); prod2[rr] = (f32x2)(1.f); }

    const f32x2 zero2 = (f32x2)(0.f);
    for (int jc = 0; jc < 64; jc += 8) {
        const float4 ua = ((const float4*)Utp)[(q0 + (jc >> 2) + 0) * kCLS + lane];
        const float4 ub = ((const float4*)Utp)[(q0 + (jc >> 2) + 1) * kCLS + lane];
        const f32x2 u01 = {ua.x, ua.y}, u23 = {ua.z, ua.w};
        const f32x2 u45 = {ub.x, ub.y}, u67 = {ub.z, ub.w};
#pragma unroll
        for (int rr = 0; rr < 16; ++rr) {
            const float4 p0 = *(const float4*)&smem.ps[wave * 16 + rr][jc];      // broadcast
            const float4 p1 = *(const float4*)&smem.ps[wave * 16 + rr][jc + 4];  // broadcast
            f32x2 tp[4];
            tp[0] = (f32x2){p0.x, p0.y} + u01;
            tp[1] = (f32x2){p0.z, p0.w} + u23;
            tp[2] = (f32x2){p1.x, p1.y} + u45;
            tp[3] = (f32x2){p1.z, p1.w} + u67;
#pragma unroll
            for (int g = 0; g < 4; ++g) {
                const f32x2 t = tp[g];
                f32x2 e;
                e.x = __builtin_amdgcn_exp2f(-__builtin_fabsf(t.x));
                e.y = __builtin_amdgcn_exp2f(-__builtin_fabsf(t.y));
                prod2[rr] = __builtin_elementwise_fma(prod2[rr], e, prod2[rr]);  // *= (1+e), <=2^32/comp
                relu2[rr] += __builtin_elementwise_max(t, zero2);
            }
        }
    }
#pragma unroll
    for (int rr = 0; rr < 16; ++rr) {
        const float contrib = relu2[rr].x + relu2[rr].y +
                              __builtin_amdgcn_logf(prod2[rr].x * prod2[rr].y);  // log2 domain
        Fpart[((size_t)ncol * kB + m0 + wave * 16 + rr) * kCLS + lane] = contrib;
    }
}

// ---------------- Final: sum 16 partials (double), softmax, argmax, one-hot ------------
__global__ __launch_bounds__(256) void softmax_final(const float* __restrict__ Fpart,
                                                     const float* __restrict__ dvec,
                                                     float* __restrict__ out) {
    const int tid = threadIdx.x;
    const int lane = tid & 63, wave = tid >> 6;
    const int row = blockIdx.x * 4 + wave;
    double s = 0.0;
#pragma unroll
    for (int k = 0; k < kHID / 64; ++k)
        s += (double)Fpart[((size_t)k * kB + row) * kCLS + lane];
    const float G = (float)s + dvec[lane] * kLog2e;  // log2-domain logit

    float m = G;
    int mi = lane;
#pragma unroll
    for (int off = 32; off; off >>= 1) {
        const float om = __shfl_xor(m, off);
        const int   oi = __shfl_xor(mi, off);
        if (om > m || (om == m && oi < mi)) { m = om; mi = oi; }  // first-index tie-break
    }
    const float e2 = __builtin_amdgcn_exp2f(G - m);
    float ssum = e2;
#pragma unroll
    for (int off = 32; off; off >>= 1) ssum += __shfl_xor(ssum, off);
    out[(size_t)row * kCLS + lane] = e2 / ssum;
    out[(size_t)kB * kCLS + (size_t)row * kCLS + lane] = (lane == mi) ? 1.0f : 0.0f;
}

// ================= Fallback (round-1, known-passing) if ws is too small =================
constexpr int BM = 64, BN = 64, BK = 16;

__global__ __launch_bounds__(256) void gemm_vw(const float* __restrict__ V,
                                               const float* __restrict__ Wm,
                                               const float* __restrict__ cvec,
                                               float* __restrict__ pre) {
    __shared__ float As[BK][BM + 4];
    __shared__ float Bs[BK][BN + 4];
    const int tid = threadIdx.x;
    const int tx = tid & 15, ty = tid >> 4;
    const int m0 = blockIdx.y * BM, n0 = blockIdx.x * BN;
    const int arow = tid >> 2, acol = (tid & 3) << 2;
    const int brow = tid >> 4, bcol = (tid & 15) << 2;
    const float* vptr = V + (size_t)(m0 + arow) * kVIS + acol;
    const float* wptr = Wm + (size_t)brow * kHID + n0 + bcol;
    float acc[4][4] = {};
    for (int k0 = 0; k0 < kVIS; k0 += BK) {
        const float4 a4 = *(const float4*)(vptr + k0);
        const float4 b4 = *(const float4*)(wptr + (size_t)k0 * kHID);
        __syncthreads();
        As[acol + 0][arow] = a4.x; As[acol + 1][arow] = a4.y;
        As[acol + 2][arow] = a4.z; As[acol + 3][arow] = a4.w;
        *(float4*)&Bs[brow][bcol] = b4;
        __syncthreads();
#pragma unroll
        for (int k = 0; k < BK; ++k) {
            const float4 av = *(const float4*)&As[k][ty << 2];
            const float4 bv = *(const float4*)&Bs[k][tx << 2];
            const float a[4] = {av.x, av.y, av.z, av.w};
            const float b[4] = {bv.x, bv.y, bv.z, bv.w};
#pragma unroll
            for (int i = 0; i < 4; ++i)
#pragma unroll
                for (int j = 0; j < 4; ++j) acc[i][j] += a[i] * b[j];
        }
    }
#pragma unroll
    for (int i = 0; i < 4; ++i) {
        const int row = m0 + (ty << 2) + i;
        const int col = n0 + (tx << 2);
        const float4 cv = *(const float4*)(cvec + col);
        float4 o;
        o.x = acc[i][0] + cv.x; o.y = acc[i][1] + cv.y;
        o.z = acc[i][2] + cv.z; o.w = acc[i][3] + cv.w;
        *(float4*)(pre + (size_t)row * kHID + col) = o;
    }
}

__device__ __forceinline__ float softplus_f(float x) {
    return fmaxf(x, 0.f) + __logf(1.f + __expf(-fabsf(x)));
}

__global__ __launch_bounds__(256) void classify(const float* __restrict__ pre,
                                                const float* __restrict__ U,
                                                const float* __restrict__ dvec,
                                                float* __restrict__ out) {
    __shared__ float preS[4][kHID];
    __shared__ float Fs[4][kCLS];
    const int tid = threadIdx.x;
    const int lane = tid & 63, wave = tid >> 6;
    const int b0 = blockIdx.x * 4;
    const float4* src = (const float4*)(pre + (size_t)b0 * kHID);
    float4* dst = (float4*)preS;
    for (int i = tid; i < kHID; i += 256) dst[i] = src[i];
    __syncthreads();
    for (int yi = 0; yi < 16; ++yi) {
        const int y = (wave << 4) + yi;
        const float* Uy = U + (size_t)y * kHID;
        float a0 = 0.f, a1 = 0.f, a2 = 0.f, a3 = 0.f;
#pragma unroll
        for (int it = 0; it < kHID / 64; ++it) {
            const int j = lane + (it << 6);
            const float u = Uy[j];
            a0 += softplus_f(preS[0][j] + u);
            a1 += softplus_f(preS[1][j] + u);
            a2 += softplus_f(preS[2][j] + u);
            a3 += softplus_f(preS[3][j] + u);
        }
        double d0 = a0, d1 = a1, d2 = a2, d3 = a3;
#pragma unroll
        for (int off = 32; off; off >>= 1) {
            d0 += __shfl_xor(d0, off); d1 += __shfl_xor(d1, off);
            d2 += __shfl_xor(d2, off); d3 += __shfl_xor(d3, off);
        }
        if (lane == 0) {
            const float dy = dvec[y];
            Fs[0][y] = (float)d0 + dy; Fs[1][y] = (float)d1 + dy;
            Fs[2][y] = (float)d2 + dy; Fs[3][y] = (float)d3 + dy;
        }
    }
    __syncthreads();
    const float F = Fs[wave][lane];
    float m = F; int mi = lane;
#pragma unroll
    for (int off = 32; off; off >>= 1) {
        const float om = __shfl_xor(m, off);
        const int oi = __shfl_xor(mi, off);
        if (om > m || (om == m && oi < mi)) { m = om; mi = oi; }
    }
    const float e = __expf(F - m);
    float s = e;
#pragma unroll
    for (int off = 32; off; off >>= 1) s += __shfl_xor(s, off);
    const int row = b0 + wave;
    out[(size_t)row * kCLS + lane] = e / s;
    out[(size_t)kB * kCLS + (size_t)row * kCLS + lane] = (lane == mi) ? 1.0f : 0.0f;
}

extern "C" void kernel_launch(void* const* d_in, const int* in_sizes, int n_in,
                              void* d_out, int out_size, void* d_ws, size_t ws_size,
                              hipStream_t stream) {
    const float* v = (const float*)d_in[0];
    const float* W = (const float*)d_in[1];
    const float* c = (const float*)d_in[2];
    const float* d = (const float*)d_in[3];
    const float* U = (const float*)d_in[4];
    float* out = (float*)d_out;
    char* ws = (char*)d_ws;

    // ws layout: vh 8MB | vl 8MB | Wt_h 4MB | Wt_l 4MB | Utp 256KB | Fpart 8MB
    const size_t need = 33816576;
    if (ws_size >= need) {
        unsigned short* vh  = (unsigned short*)(ws);
        unsigned short* vl  = (unsigned short*)(ws + 8388608);
        unsigned short* wth = (unsigned short*)(ws + 16777216);
        unsigned short* wtl = (unsigned short*)(ws + 20971520);
        float* Utp   = (float*)(ws + 25165824);
        float* Fpart = (float*)(ws + 25427968);
        prep_all<<<6400, 256, 0, stream>>>(v, W, U, vh, vl, wth, wtl, Utp);
        gemm_fused<<<512, 256, 0, stream>>>(vh, vl, wth, wtl, c, Utp, Fpart);
        softmax_final<<<kB / 4, 256, 0, stream>>>(Fpart, d, out);
    } else {
        float* pre = (float*)ws;
        gemm_vw<<<dim3(kHID / BN, kB / BM), 256, 0, stream>>>(v, W, c, pre);
        classify<<<kB / 4, 256, 0, stream>>>(pre, U, d, out);
    }
}